// Round 1
// baseline (2947.882 us; speedup 1.0000x reference)
//
#include <hip/hip_runtime.h>
#include <hip/hip_bf16.h>
#include <math.h>

// ---------------------------------------------------------------------------
// DeformTransformerDecoderLayer forward, MI355X
// B=2, C=256, N=1024, F=2048, heads=8, dh=32, levels=3, points=4
// Levels: (200,176), (200,176), (400,352)
// ---------------------------------------------------------------------------

__device__ inline void store_val(float* p, float v) { *p = v; }
__device__ inline void store_val(__hip_bfloat16* p, float v) { *p = __float2bfloat16(v); }

// out[m,n] = sum_k A[m,k] * W[n,k] + bias[n]   (optionally relu)
// AT=true: A is [K, M] row-major with row stride lda (channels-major feature map)
template<bool AT, typename OutT>
__global__ __launch_bounds__(256) void gemm_kernel(
    const float* __restrict__ A, long lda,
    const float* __restrict__ W,
    const float* __restrict__ bias,
    OutT* __restrict__ out, long ldo,
    int M, int Nn, int K, int relu)
{
  __shared__ float As[16][65];
  __shared__ float Ws[16][65];
  int tid = threadIdx.x;
  int tx = tid & 15, ty = tid >> 4;
  int m0 = blockIdx.x * 64, n0 = blockIdx.y * 64;
  float acc[4][4] = {};

  for (int k0 = 0; k0 < K; k0 += 16) {
    if (AT) {
      #pragma unroll
      for (int i = 0; i < 4; ++i) {
        int idx = tid + i * 256;
        int kk = idx >> 6, mm = idx & 63;
        int m = m0 + mm;
        As[kk][mm] = (m < M) ? A[(long)(k0 + kk) * lda + m] : 0.f;
      }
    } else {
      #pragma unroll
      for (int i = 0; i < 4; ++i) {
        int idx = tid + i * 256;
        int mm = idx >> 4, kk = idx & 15;
        int m = m0 + mm;
        As[kk][mm] = (m < M) ? A[(long)m * lda + k0 + kk] : 0.f;
      }
    }
    #pragma unroll
    for (int i = 0; i < 4; ++i) {
      int idx = tid + i * 256;
      int nn = idx >> 4, kk = idx & 15;
      int n = n0 + nn;
      Ws[kk][nn] = (n < Nn) ? W[(long)n * K + k0 + kk] : 0.f;
    }
    __syncthreads();
    #pragma unroll
    for (int kk = 0; kk < 16; ++kk) {
      float a[4], bb[4];
      #pragma unroll
      for (int i = 0; i < 4; ++i) a[i] = As[kk][ty * 4 + i];
      #pragma unroll
      for (int j = 0; j < 4; ++j) bb[j] = Ws[kk][tx * 4 + j];
      #pragma unroll
      for (int i = 0; i < 4; ++i)
        #pragma unroll
        for (int j = 0; j < 4; ++j)
          acc[i][j] += a[i] * bb[j];
    }
    __syncthreads();
  }

  #pragma unroll
  for (int i = 0; i < 4; ++i) {
    int m = m0 + ty * 4 + i;
    if (m >= M) continue;
    #pragma unroll
    for (int j = 0; j < 4; ++j) {
      int n = n0 + tx * 4 + j;
      if (n >= Nn) continue;
      float v = acc[i][j] + bias[n];
      if (relu) v = fmaxf(v, 0.f);
      store_val(&out[(long)m * ldo + n], v);
    }
  }
}

// in [B, R, Cc] -> out [B, Cc, R]
__global__ __launch_bounds__(256) void transpose_kernel(
    const float* __restrict__ in, float* __restrict__ out, int R, int Cc)
{
  __shared__ float tile[32][33];
  int b = blockIdx.z;
  int c0 = blockIdx.x << 5, r0 = blockIdx.y << 5;
  int tx = threadIdx.x, ty = threadIdx.y;  // 32 x 8
  const float* inb = in + (size_t)b * R * Cc;
  float* outb = out + (size_t)b * R * Cc;
  #pragma unroll
  for (int i = 0; i < 32; i += 8)
    tile[ty + i][tx] = inb[(size_t)(r0 + ty + i) * Cc + c0 + tx];
  __syncthreads();
  #pragma unroll
  for (int i = 0; i < 32; i += 8)
    outb[(size_t)(c0 + ty + i) * R + r0 + tx] = tile[tx][ty + i];
}

// One block per (b, h, n). qkv: [B*N, 768] = [q | k | v], each [h=8][dh=32]
__global__ __launch_bounds__(256) void attn_kernel(
    const float* __restrict__ qkv, float* __restrict__ sa)
{
  const int N = 1024;
  int idx = blockIdx.x;
  int n = idx & (N - 1);
  int h = (idx >> 10) & 7;
  int b = idx >> 13;
  int t = threadIdx.x;

  __shared__ float qv[32];
  __shared__ float sp[1024];
  __shared__ float red[256];
  __shared__ float part[8][32];

  if (t < 32)
    qv[t] = qkv[((size_t)(b * N + n)) * 768 + h * 32 + t] * 0.17677669529663687f; // 1/sqrt(32)
  __syncthreads();

  #pragma unroll
  for (int i = 0; i < 4; ++i) {
    int m = t + i * 256;
    const float* kp = qkv + ((size_t)(b * N + m)) * 768 + 256 + h * 32;
    float s = 0.f;
    #pragma unroll
    for (int d2 = 0; d2 < 32; ++d2) s += qv[d2] * kp[d2];
    sp[m] = s;
  }
  __syncthreads();

  float mx = fmaxf(fmaxf(sp[t], sp[t + 256]), fmaxf(sp[t + 512], sp[t + 768]));
  red[t] = mx;
  __syncthreads();
  for (int s2 = 128; s2 > 0; s2 >>= 1) {
    if (t < s2) red[t] = fmaxf(red[t], red[t + s2]);
    __syncthreads();
  }
  mx = red[0];
  __syncthreads();

  float lsum = 0.f;
  #pragma unroll
  for (int i = 0; i < 4; ++i) {
    int m = t + i * 256;
    float e = __expf(sp[m] - mx);
    sp[m] = e;
    lsum += e;
  }
  red[t] = lsum;
  __syncthreads();
  for (int s2 = 128; s2 > 0; s2 >>= 1) {
    if (t < s2) red[t] += red[t + s2];
    __syncthreads();
  }
  float inv = 1.f / red[0];

  int tg = t >> 5, d = t & 31;
  float acc = 0.f;
  const float* vbase = qkv + 512 + h * 32 + d;
  for (int m = tg * 128; m < tg * 128 + 128; ++m)
    acc += sp[m] * vbase[((size_t)(b * N + m)) * 768];
  part[tg][d] = acc;
  __syncthreads();
  if (tg == 0) {
    float o = 0.f;
    #pragma unroll
    for (int g = 0; g < 8; ++g) o += part[g][d];
    sa[((size_t)(b * N + n)) * 256 + h * 32 + d] = o * inv;
  }
}

// out = LayerNorm(x + res) * g + be, row = (b,n), C = 256
__global__ __launch_bounds__(256) void add_ln_kernel(
    const float* __restrict__ x, const float* __restrict__ res,
    const float* __restrict__ g, const float* __restrict__ be,
    float* __restrict__ out)
{
  int row = blockIdx.x, c = threadIdx.x;
  size_t base = (size_t)row * 256;
  float v = x[base + c] + res[base + c];
  __shared__ float red[256];
  red[c] = v;
  __syncthreads();
  for (int s = 128; s > 0; s >>= 1) { if (c < s) red[c] += red[c + s]; __syncthreads(); }
  float mean = red[0] * (1.f / 256.f);
  __syncthreads();
  float dv = v - mean;
  red[c] = dv * dv;
  __syncthreads();
  for (int s = 128; s > 0; s >>= 1) { if (c < s) red[c] += red[c + s]; __syncthreads(); }
  float var = red[0] * (1.f / 256.f);
  out[base + c] = dv * rsqrtf(var + 1e-5f) * g[c] + be[c];
}

// One block per (b,n); thread = (head h = t>>5, channel d = t&31)
__global__ __launch_bounds__(256) void deform_kernel(
    const float* __restrict__ query_pos,
    const float* __restrict__ offv,   // [B*N, 192] = [h][l][p][2]
    const float* __restrict__ awv,    // [B*N, 96]  = [h][l*p]
    const __hip_bfloat16* __restrict__ v0,
    const __hip_bfloat16* __restrict__ v1,
    const __hip_bfloat16* __restrict__ v2,
    float* __restrict__ ca)
{
  const int N = 1024;
  int bn = blockIdx.x;
  int b = bn >> 10;
  int t = threadIdx.x;
  int hh = t >> 5, d = t & 31;

  // softmax over the 24 attention weights for this head (redundant per lane; L1-cached)
  const float* awp = awv + (size_t)bn * 96 + hh * 24;
  float w[24];
  float mx = -1e30f;
  #pragma unroll
  for (int i = 0; i < 24; ++i) { w[i] = awp[i]; mx = fmaxf(mx, w[i]); }
  float s = 0.f;
  #pragma unroll
  for (int i = 0; i < 24; ++i) { w[i] = __expf(w[i] - mx); s += w[i]; }
  float inv = 1.f / s;

  float rx = query_pos[bn * 2 + 0] * (1.f / 352.f);
  float ry = query_pos[bn * 2 + 1] * (1.f / 400.f);
  const float* offp = offv + (size_t)bn * 192 + hh * 24;

  const __hip_bfloat16* vb[3] = {v0, v1, v2};
  const int Hs[3] = {200, 200, 400};
  const int Wss[3] = {176, 176, 352};

  float acc = 0.f;
  #pragma unroll
  for (int l = 0; l < 3; ++l) {
    int H = Hs[l], W = Wss[l], HW = H * W;
    const __hip_bfloat16* vl = vb[l] + (size_t)b * HW * 256 + hh * 32 + d;
    float fx = rx * (float)W, fy = ry * (float)H;
    #pragma unroll
    for (int p = 0; p < 4; ++p) {
      float x = fx + offp[l * 8 + p * 2 + 0] - 0.5f;
      float y = fy + offp[l * 8 + p * 2 + 1] - 0.5f;
      float x0f = floorf(x), y0f = floorf(y);
      float wx = x - x0f, wy = y - y0f;
      int x0 = (int)x0f, y0 = (int)y0f;
      float wgt = w[l * 4 + p] * inv;
      bool xin0 = (x0 >= 0) & (x0 < W);
      bool xin1 = (x0 + 1 >= 0) & (x0 + 1 < W);
      bool yin0 = (y0 >= 0) & (y0 < H);
      bool yin1 = (y0 + 1 >= 0) & (y0 + 1 < H);
      float v00 = 0.f, v10 = 0.f, v01 = 0.f, v11 = 0.f;
      if (yin0) {
        size_t rowo = (size_t)(y0 * W) * 256;
        if (xin0) v00 = __bfloat162float(vl[rowo + (size_t)x0 * 256]);
        if (xin1) v10 = __bfloat162float(vl[rowo + (size_t)(x0 + 1) * 256]);
      }
      if (yin1) {
        size_t rowo = (size_t)((y0 + 1) * W) * 256;
        if (xin0) v01 = __bfloat162float(vl[rowo + (size_t)x0 * 256]);
        if (xin1) v11 = __bfloat162float(vl[rowo + (size_t)(x0 + 1) * 256]);
      }
      acc += wgt * ((1.f - wx) * (1.f - wy) * v00 + wx * (1.f - wy) * v10 +
                    (1.f - wx) * wy * v01 + wx * wy * v11);
    }
  }
  ca[(size_t)bn * 256 + t] = acc;
}

extern "C" void kernel_launch(void* const* d_in, const int* in_sizes, int n_in,
                              void* d_out, int out_size, void* d_ws, size_t ws_size,
                              hipStream_t stream)
{
  const float* query      = (const float*)d_in[0];
  const float* query_pos  = (const float*)d_in[1];
  const float* bev        = (const float*)d_in[2];
  const float* x_conv4    = (const float*)d_in[3];
  const float* x_conv3    = (const float*)d_in[4];
  const float* in_proj_w  = (const float*)d_in[5];
  const float* in_proj_b  = (const float*)d_in[6];
  const float* out_proj_w = (const float*)d_in[7];
  const float* out_proj_b = (const float*)d_in[8];
  const float* w_off      = (const float*)d_in[9];
  const float* b_off      = (const float*)d_in[10];
  const float* w_attn     = (const float*)d_in[11];
  const float* b_attn     = (const float*)d_in[12];
  const float* w_val      = (const float*)d_in[13];
  const float* b_val      = (const float*)d_in[14];
  const float* w_out      = (const float*)d_in[15];
  const float* b_out      = (const float*)d_in[16];
  const float* w_ff1      = (const float*)d_in[17];
  const float* b_ff1      = (const float*)d_in[18];
  const float* w_ff2      = (const float*)d_in[19];
  const float* b_ff2      = (const float*)d_in[20];
  const float* g1         = (const float*)d_in[21];
  const float* be1        = (const float*)d_in[22];
  const float* g2         = (const float*)d_in[23];
  const float* be2        = (const float*)d_in[24];
  const float* g3         = (const float*)d_in[25];
  const float* be3        = (const float*)d_in[26];

  const int B = 2, N = 1024, C = 256, F = 2048;
  const int BN = B * N;

  char* wp = (char*)d_ws;
  auto alloc = [&](size_t bytes) -> void* {
    void* p = (void*)wp;
    wp += (bytes + 255) & ~(size_t)255;
    return p;
  };
  float* q0   = (float*)alloc((size_t)BN * C * 4);
  float* qkv  = (float*)alloc((size_t)BN * 3 * C * 4);
  float* sa   = (float*)alloc((size_t)BN * C * 4);
  float* tmp  = (float*)alloc((size_t)BN * C * 4);
  float* q1   = (float*)alloc((size_t)BN * C * 4);
  float* q2   = (float*)alloc((size_t)BN * C * 4);
  float* q3   = (float*)alloc((size_t)BN * C * 4);
  float* offb = (float*)alloc((size_t)BN * 192 * 4);
  float* awb  = (float*)alloc((size_t)BN * 96 * 4);
  float* ca   = (float*)alloc((size_t)BN * C * 4);
  float* ff   = (float*)alloc((size_t)BN * F * 4);
  __hip_bfloat16* v0 = (__hip_bfloat16*)alloc((size_t)B * 35200 * C * 2);
  __hip_bfloat16* v1 = (__hip_bfloat16*)alloc((size_t)B * 35200 * C * 2);
  __hip_bfloat16* v2 = (__hip_bfloat16*)alloc((size_t)B * 140800 * C * 2);

  dim3 tb(32, 8);

  // q0 = transpose(query): [B, C, N] -> [B, N, C]
  transpose_kernel<<<dim3(N / 32, C / 32, B), tb, 0, stream>>>(query, q0, C, N);

  // qkv = q0 @ in_proj_w.T + in_proj_b : [BN, 768]
  gemm_kernel<false, float><<<dim3(BN / 64, 768 / 64), 256, 0, stream>>>(
      q0, C, in_proj_w, in_proj_b, qkv, 768, BN, 768, C, 0);

  // self-attention
  attn_kernel<<<dim3(B * 8 * N), 256, 0, stream>>>(qkv, sa);

  // out proj + LN1
  gemm_kernel<false, float><<<dim3(BN / 64, C / 64), 256, 0, stream>>>(
      sa, C, out_proj_w, out_proj_b, tmp, C, BN, C, C, 0);
  add_ln_kernel<<<dim3(BN), 256, 0, stream>>>(tmp, q0, g1, be1, q1);

  // value projections (channels-major feature maps, AT path), bf16 output
  {
    const float* feats[3] = {bev, x_conv4, x_conv3};
    __hip_bfloat16* vals[3] = {v0, v1, v2};
    const int HWs[3] = {35200, 35200, 140800};
    for (int l = 0; l < 3; ++l)
      for (int b = 0; b < B; ++b)
        gemm_kernel<true, __hip_bfloat16><<<dim3(HWs[l] / 64, C / 64), 256, 0, stream>>>(
            feats[l] + (size_t)b * C * HWs[l], HWs[l], w_val, b_val,
            vals[l] + (size_t)b * HWs[l] * C, C, HWs[l], C, C, 0);
  }

  // sampling offsets + attention weights
  gemm_kernel<false, float><<<dim3(BN / 64, 3), 256, 0, stream>>>(
      q1, C, w_off, b_off, offb, 192, BN, 192, C, 0);
  gemm_kernel<false, float><<<dim3(BN / 64, 2), 256, 0, stream>>>(
      q1, C, w_attn, b_attn, awb, 96, BN, 96, C, 0);

  // deformable sampling
  deform_kernel<<<dim3(BN), 256, 0, stream>>>(query_pos, offb, awb, v0, v1, v2, ca);

  // cross-attn output proj + LN2
  gemm_kernel<false, float><<<dim3(BN / 64, C / 64), 256, 0, stream>>>(
      ca, C, w_out, b_out, tmp, C, BN, C, C, 0);
  add_ln_kernel<<<dim3(BN), 256, 0, stream>>>(tmp, q1, g2, be2, q2);

  // FFN + LN3
  gemm_kernel<false, float><<<dim3(BN / 64, F / 64), 256, 0, stream>>>(
      q2, C, w_ff1, b_ff1, ff, F, BN, F, C, 1);
  gemm_kernel<false, float><<<dim3(BN / 64, C / 64), 256, 0, stream>>>(
      ff, F, w_ff2, b_ff2, tmp, C, BN, C, F, 0);
  add_ln_kernel<<<dim3(BN), 256, 0, stream>>>(tmp, q2, g3, be3, q3);

  // final transpose [B, N, C] -> [B, C, N]
  transpose_kernel<<<dim3(C / 32, N / 32, B), tb, 0, stream>>>(q3, (float*)d_out, N, C);
}

// Round 2
// 1732.044 us; speedup vs baseline: 1.7020x; 1.7020x over previous
//
#include <hip/hip_runtime.h>
#include <hip/hip_bf16.h>
#include <math.h>

// ---------------------------------------------------------------------------
// DeformTransformerDecoderLayer forward, MI355X
// B=2, C=256, N=1024, F=2048, heads=8, dh=32, levels=3, points=4
// Levels: (200,176), (200,176), (400,352)
// ---------------------------------------------------------------------------

__device__ inline void store8(float* p, const float v[8]) {
  *(float4*)p       = make_float4(v[0], v[1], v[2], v[3]);
  *(float4*)(p + 4) = make_float4(v[4], v[5], v[6], v[7]);
}
__device__ inline void store8(__hip_bfloat16* p, const float v[8]) {
  union { unsigned short u[8]; uint4 q; } pk;
  #pragma unroll
  for (int j = 0; j < 8; ++j)
    ((__hip_bfloat16*)pk.u)[j] = __float2bfloat16(v[j]);
  *(uint4*)p = pk.q;
}

// ---------------------------------------------------------------------------
// Big GEMM: out[m,n] = sum_k A[m,k] * W[n,k] + bias[n]  (optional relu)
// AT=true: A is [K, M] row-major with row stride lda (channels-major feats).
// Tile 128x128, 256 threads, 8x8 acc per thread. No edge guards: all callers
// use M%128==0, N%128==0, K%16==0. blockIdx.z batches via abstride/obstride.
// ---------------------------------------------------------------------------
template<bool AT, typename OutT>
__global__ __launch_bounds__(256) void gemm128_kernel(
    const float* __restrict__ A, long lda, long abstride,
    const float* __restrict__ W,
    const float* __restrict__ bias,
    OutT* __restrict__ out, long ldo, long obstride,
    int K, int relu)
{
  __shared__ float As[16][136];
  __shared__ float Ws[16][136];
  int t = threadIdx.x;
  int tx = t & 15, ty = t >> 4;
  long m0 = (long)blockIdx.x * 128, n0 = (long)blockIdx.y * 128;
  A += (long)blockIdx.z * abstride;
  out += (long)blockIdx.z * obstride;
  float acc[8][8] = {};

  for (int k0 = 0; k0 < K; k0 += 16) {
    // stage A into regs
    float av[8];
    int a_kk = 0, a_mm = 0, a_kc = 0;
    if (AT) {
      a_kk = t >> 4; a_mm = (t & 15) * 8;
      const float* src = A + (long)(k0 + a_kk) * lda + m0 + a_mm;
      *(float4*)&av[0] = *(const float4*)src;
      *(float4*)&av[4] = *(const float4*)(src + 4);
    } else {
      a_mm = t >> 1; a_kc = (t & 1) * 8;
      const float* src = A + (m0 + a_mm) * lda + k0 + a_kc;
      *(float4*)&av[0] = *(const float4*)src;
      *(float4*)&av[4] = *(const float4*)(src + 4);
    }
    // stage W into regs
    float wv[8];
    int w_n = t >> 1, w_kc = (t & 1) * 8;
    {
      const float* src = W + (long)(n0 + w_n) * K + k0 + w_kc;
      *(float4*)&wv[0] = *(const float4*)src;
      *(float4*)&wv[4] = *(const float4*)(src + 4);
    }
    __syncthreads();
    if (AT) {
      *(float4*)&As[a_kk][a_mm]     = *(float4*)&av[0];
      *(float4*)&As[a_kk][a_mm + 4] = *(float4*)&av[4];
    } else {
      #pragma unroll
      for (int j = 0; j < 8; ++j) As[a_kc + j][a_mm] = av[j];
    }
    #pragma unroll
    for (int j = 0; j < 8; ++j) Ws[w_kc + j][w_n] = wv[j];
    __syncthreads();

    #pragma unroll
    for (int kk = 0; kk < 16; ++kk) {
      float a[8], b[8];
      *(float4*)&a[0] = *(float4*)&As[kk][ty * 8];
      *(float4*)&a[4] = *(float4*)&As[kk][ty * 8 + 4];
      *(float4*)&b[0] = *(float4*)&Ws[kk][tx * 8];
      *(float4*)&b[4] = *(float4*)&Ws[kk][tx * 8 + 4];
      #pragma unroll
      for (int i = 0; i < 8; ++i)
        #pragma unroll
        for (int j = 0; j < 8; ++j)
          acc[i][j] = fmaf(a[i], b[j], acc[i][j]);
    }
  }

  float bl[8];
  #pragma unroll
  for (int j = 0; j < 8; ++j) bl[j] = bias[n0 + tx * 8 + j];
  #pragma unroll
  for (int i = 0; i < 8; ++i) {
    float v[8];
    #pragma unroll
    for (int j = 0; j < 8; ++j) {
      float x = acc[i][j] + bl[j];
      v[j] = relu ? fmaxf(x, 0.f) : x;
    }
    store8(&out[(m0 + ty * 8 + i) * ldo + n0 + tx * 8], v);
  }
}

// ---------------------------------------------------------------------------
// Small GEMM (kept for N=192 / N=96 projections): 64x64 tile, 4x4 per thread
// ---------------------------------------------------------------------------
__global__ __launch_bounds__(256) void gemm_kernel(
    const float* __restrict__ A, long lda,
    const float* __restrict__ W,
    const float* __restrict__ bias,
    float* __restrict__ out, long ldo,
    int M, int Nn, int K, int relu)
{
  __shared__ float As[16][65];
  __shared__ float Ws[16][65];
  int tid = threadIdx.x;
  int tx = tid & 15, ty = tid >> 4;
  int m0 = blockIdx.x * 64, n0 = blockIdx.y * 64;
  float acc[4][4] = {};

  for (int k0 = 0; k0 < K; k0 += 16) {
    #pragma unroll
    for (int i = 0; i < 4; ++i) {
      int idx = tid + i * 256;
      int mm = idx >> 4, kk = idx & 15;
      int m = m0 + mm;
      As[kk][mm] = (m < M) ? A[(long)m * lda + k0 + kk] : 0.f;
    }
    #pragma unroll
    for (int i = 0; i < 4; ++i) {
      int idx = tid + i * 256;
      int nn = idx >> 4, kk = idx & 15;
      int n = n0 + nn;
      Ws[kk][nn] = (n < Nn) ? W[(long)n * K + k0 + kk] : 0.f;
    }
    __syncthreads();
    #pragma unroll
    for (int kk = 0; kk < 16; ++kk) {
      float a[4], bb[4];
      #pragma unroll
      for (int i = 0; i < 4; ++i) a[i] = As[kk][ty * 4 + i];
      #pragma unroll
      for (int j = 0; j < 4; ++j) bb[j] = Ws[kk][tx * 4 + j];
      #pragma unroll
      for (int i = 0; i < 4; ++i)
        #pragma unroll
        for (int j = 0; j < 4; ++j)
          acc[i][j] += a[i] * bb[j];
    }
    __syncthreads();
  }

  #pragma unroll
  for (int i = 0; i < 4; ++i) {
    int m = m0 + ty * 4 + i;
    if (m >= M) continue;
    #pragma unroll
    for (int j = 0; j < 4; ++j) {
      int n = n0 + tx * 4 + j;
      if (n >= Nn) continue;
      float v = acc[i][j] + bias[n];
      if (relu) v = fmaxf(v, 0.f);
      out[(long)m * ldo + n] = v;
    }
  }
}

// in [B, R, Cc] -> out [B, Cc, R]
__global__ __launch_bounds__(256) void transpose_kernel(
    const float* __restrict__ in, float* __restrict__ out, int R, int Cc)
{
  __shared__ float tile[32][33];
  int b = blockIdx.z;
  int c0 = blockIdx.x << 5, r0 = blockIdx.y << 5;
  int tx = threadIdx.x, ty = threadIdx.y;  // 32 x 8
  const float* inb = in + (size_t)b * R * Cc;
  float* outb = out + (size_t)b * R * Cc;
  #pragma unroll
  for (int i = 0; i < 32; i += 8)
    tile[ty + i][tx] = inb[(size_t)(r0 + ty + i) * Cc + c0 + tx];
  __syncthreads();
  #pragma unroll
  for (int i = 0; i < 32; i += 8)
    outb[(size_t)(c0 + ty + i) * R + r0 + tx] = tile[tx][ty + i];
}

// ---------------------------------------------------------------------------
// Flash-style self-attention. Grid (B*8, N/64), 256 threads.
// Thread t: query row r = t>>2 (of 64), group c4 = t&3.
//   scores: c4 covers kv cols [c4*16, c4*16+16); PV: c4 covers d [c4*8, c4*8+8)
// Row softmax state (m,l) reduced across the 4 lanes of a row via shfl_xor.
// ---------------------------------------------------------------------------
__global__ __launch_bounds__(256) void flash_attn_kernel(
    const float* __restrict__ qkv, float* __restrict__ sa)
{
  const int N = 1024;
  int bh = blockIdx.x;
  int b = bh >> 3, h = bh & 7;
  int q0 = blockIdx.y * 64;
  int t = threadIdx.x;
  int r = t >> 2, c4 = t & 3;

  __shared__ float Qs[64][36];
  __shared__ float Ks[64][36];
  __shared__ float Vs[64][36];
  __shared__ float Ps[64][68];

  // load Q tile, scaled by 1/sqrt(dh)
  {
    int row = t >> 2, col = (t & 3) * 8;
    const float* src = qkv + ((size_t)(b * N + q0 + row)) * 768 + h * 32 + col;
    float4 v0 = *(const float4*)src;
    float4 v1 = *(const float4*)(src + 4);
    const float s = 0.17677669529663687f;
    v0.x *= s; v0.y *= s; v0.z *= s; v0.w *= s;
    v1.x *= s; v1.y *= s; v1.z *= s; v1.w *= s;
    *(float4*)&Qs[row][col] = v0;
    *(float4*)&Qs[row][col + 4] = v1;
  }
  __syncthreads();
  float qreg[32];
  #pragma unroll
  for (int k = 0; k < 8; ++k)
    *(float4*)&qreg[k * 4] = *(float4*)&Qs[r][k * 4];

  float o[8] = {};
  float m = -INFINITY, l = 0.f;

  for (int kt = 0; kt < 16; ++kt) {
    // load K/V tile to regs
    int row = t >> 2, col = (t & 3) * 8;
    const float* kp = qkv + ((size_t)(b * N + kt * 64 + row)) * 768 + 256 + h * 32 + col;
    float4 k0 = *(const float4*)kp;
    float4 k1 = *(const float4*)(kp + 4);
    float4 v0 = *(const float4*)(kp + 256);
    float4 v1 = *(const float4*)(kp + 260);
    __syncthreads();  // previous tile's PV done
    *(float4*)&Ks[row][col] = k0;  *(float4*)&Ks[row][col + 4] = k1;
    *(float4*)&Vs[row][col] = v0;  *(float4*)&Vs[row][col + 4] = v1;
    __syncthreads();

    // scores for my 16 kv columns
    float sc[16];
    #pragma unroll
    for (int jj = 0; jj < 16; ++jj) {
      int j = c4 * 16 + jj;
      float s = 0.f;
      #pragma unroll
      for (int k8 = 0; k8 < 8; ++k8) {
        float4 kk4 = *(float4*)&Ks[j][k8 * 4];
        s = fmaf(qreg[k8 * 4 + 0], kk4.x, s);
        s = fmaf(qreg[k8 * 4 + 1], kk4.y, s);
        s = fmaf(qreg[k8 * 4 + 2], kk4.z, s);
        s = fmaf(qreg[k8 * 4 + 3], kk4.w, s);
      }
      sc[jj] = s;
    }
    float tm = sc[0];
    #pragma unroll
    for (int jj = 1; jj < 16; ++jj) tm = fmaxf(tm, sc[jj]);
    tm = fmaxf(tm, __shfl_xor(tm, 1));
    tm = fmaxf(tm, __shfl_xor(tm, 2));
    float mn = fmaxf(m, tm);
    float alpha = __expf(m - mn);
    float ls = 0.f;
    #pragma unroll
    for (int jj = 0; jj < 16; ++jj) {
      float p = __expf(sc[jj] - mn);
      Ps[r][c4 * 16 + jj] = p;
      ls += p;
    }
    ls += __shfl_xor(ls, 1);
    ls += __shfl_xor(ls, 2);
    l = l * alpha + ls;
    m = mn;
    #pragma unroll
    for (int d = 0; d < 8; ++d) o[d] *= alpha;
    __syncthreads();

    // PV: my 8 d-channels
    #pragma unroll 4
    for (int j = 0; j < 64; ++j) {
      float p = Ps[r][j];
      float4 w0 = *(float4*)&Vs[j][c4 * 8];
      float4 w1 = *(float4*)&Vs[j][c4 * 8 + 4];
      o[0] = fmaf(p, w0.x, o[0]); o[1] = fmaf(p, w0.y, o[1]);
      o[2] = fmaf(p, w0.z, o[2]); o[3] = fmaf(p, w0.w, o[3]);
      o[4] = fmaf(p, w1.x, o[4]); o[5] = fmaf(p, w1.y, o[5]);
      o[6] = fmaf(p, w1.z, o[6]); o[7] = fmaf(p, w1.w, o[7]);
    }
  }

  float inv = 1.f / l;
  float vout[8];
  #pragma unroll
  for (int d = 0; d < 8; ++d) vout[d] = o[d] * inv;
  store8(&sa[((size_t)(b * N + q0 + r)) * 256 + h * 32 + c4 * 8], vout);
}

// out = LayerNorm(x + res) * g + be, row = (b,n), C = 256
__global__ __launch_bounds__(256) void add_ln_kernel(
    const float* __restrict__ x, const float* __restrict__ res,
    const float* __restrict__ g, const float* __restrict__ be,
    float* __restrict__ out)
{
  int row = blockIdx.x, c = threadIdx.x;
  size_t base = (size_t)row * 256;
  float v = x[base + c] + res[base + c];
  __shared__ float red[256];
  red[c] = v;
  __syncthreads();
  for (int s = 128; s > 0; s >>= 1) { if (c < s) red[c] += red[c + s]; __syncthreads(); }
  float mean = red[0] * (1.f / 256.f);
  __syncthreads();
  float dv = v - mean;
  red[c] = dv * dv;
  __syncthreads();
  for (int s = 128; s > 0; s >>= 1) { if (c < s) red[c] += red[c + s]; __syncthreads(); }
  float var = red[0] * (1.f / 256.f);
  out[base + c] = dv * rsqrtf(var + 1e-5f) * g[c] + be[c];
}

// One block per (b,n); thread = (head h = t>>5, channel d = t&31)
__global__ __launch_bounds__(256) void deform_kernel(
    const float* __restrict__ query_pos,
    const float* __restrict__ offv,   // [B*N, 192] = [h][l][p][2]
    const float* __restrict__ awv,    // [B*N, 96]  = [h][l*p]
    const __hip_bfloat16* __restrict__ v0,
    const __hip_bfloat16* __restrict__ v1,
    const __hip_bfloat16* __restrict__ v2,
    float* __restrict__ ca)
{
  const int N = 1024;
  int bn = blockIdx.x;
  int b = bn >> 10;
  int t = threadIdx.x;
  int hh = t >> 5, d = t & 31;

  const float* awp = awv + (size_t)bn * 96 + hh * 24;
  float w[24];
  float mx = -1e30f;
  #pragma unroll
  for (int i = 0; i < 24; ++i) { w[i] = awp[i]; mx = fmaxf(mx, w[i]); }
  float s = 0.f;
  #pragma unroll
  for (int i = 0; i < 24; ++i) { w[i] = __expf(w[i] - mx); s += w[i]; }
  float inv = 1.f / s;

  float rx = query_pos[bn * 2 + 0] * (1.f / 352.f);
  float ry = query_pos[bn * 2 + 1] * (1.f / 400.f);
  const float* offp = offv + (size_t)bn * 192 + hh * 24;

  const __hip_bfloat16* vb[3] = {v0, v1, v2};
  const int Hs[3] = {200, 200, 400};
  const int Wss[3] = {176, 176, 352};

  float acc = 0.f;
  #pragma unroll
  for (int l = 0; l < 3; ++l) {
    int H = Hs[l], W = Wss[l], HW = H * W;
    const __hip_bfloat16* vl = vb[l] + (size_t)b * HW * 256 + hh * 32 + d;
    float fx = rx * (float)W, fy = ry * (float)H;
    #pragma unroll
    for (int p = 0; p < 4; ++p) {
      float x = fx + offp[l * 8 + p * 2 + 0] - 0.5f;
      float y = fy + offp[l * 8 + p * 2 + 1] - 0.5f;
      float x0f = floorf(x), y0f = floorf(y);
      float wx = x - x0f, wy = y - y0f;
      int x0 = (int)x0f, y0 = (int)y0f;
      float wgt = w[l * 4 + p] * inv;
      bool xin0 = (x0 >= 0) & (x0 < W);
      bool xin1 = (x0 + 1 >= 0) & (x0 + 1 < W);
      bool yin0 = (y0 >= 0) & (y0 < H);
      bool yin1 = (y0 + 1 >= 0) & (y0 + 1 < H);
      float v00 = 0.f, v10 = 0.f, v01 = 0.f, v11 = 0.f;
      if (yin0) {
        size_t rowo = (size_t)(y0 * W) * 256;
        if (xin0) v00 = __bfloat162float(vl[rowo + (size_t)x0 * 256]);
        if (xin1) v10 = __bfloat162float(vl[rowo + (size_t)(x0 + 1) * 256]);
      }
      if (yin1) {
        size_t rowo = (size_t)((y0 + 1) * W) * 256;
        if (xin0) v01 = __bfloat162float(vl[rowo + (size_t)x0 * 256]);
        if (xin1) v11 = __bfloat162float(vl[rowo + (size_t)(x0 + 1) * 256]);
      }
      acc += wgt * ((1.f - wx) * (1.f - wy) * v00 + wx * (1.f - wy) * v10 +
                    (1.f - wx) * wy * v01 + wx * wy * v11);
    }
  }
  ca[(size_t)bn * 256 + t] = acc;
}

extern "C" void kernel_launch(void* const* d_in, const int* in_sizes, int n_in,
                              void* d_out, int out_size, void* d_ws, size_t ws_size,
                              hipStream_t stream)
{
  const float* query      = (const float*)d_in[0];
  const float* query_pos  = (const float*)d_in[1];
  const float* bev        = (const float*)d_in[2];
  const float* x_conv4    = (const float*)d_in[3];
  const float* x_conv3    = (const float*)d_in[4];
  const float* in_proj_w  = (const float*)d_in[5];
  const float* in_proj_b  = (const float*)d_in[6];
  const float* out_proj_w = (const float*)d_in[7];
  const float* out_proj_b = (const float*)d_in[8];
  const float* w_off      = (const float*)d_in[9];
  const float* b_off      = (const float*)d_in[10];
  const float* w_attn     = (const float*)d_in[11];
  const float* b_attn     = (const float*)d_in[12];
  const float* w_val      = (const float*)d_in[13];
  const float* b_val      = (const float*)d_in[14];
  const float* w_out      = (const float*)d_in[15];
  const float* b_out      = (const float*)d_in[16];
  const float* w_ff1      = (const float*)d_in[17];
  const float* b_ff1      = (const float*)d_in[18];
  const float* w_ff2      = (const float*)d_in[19];
  const float* b_ff2      = (const float*)d_in[20];
  const float* g1         = (const float*)d_in[21];
  const float* be1        = (const float*)d_in[22];
  const float* g2         = (const float*)d_in[23];
  const float* be2        = (const float*)d_in[24];
  const float* g3         = (const float*)d_in[25];
  const float* be3        = (const float*)d_in[26];

  const int B = 2, N = 1024, C = 256, F = 2048;
  const int BN = B * N;

  char* wp = (char*)d_ws;
  auto alloc = [&](size_t bytes) -> void* {
    void* p = (void*)wp;
    wp += (bytes + 255) & ~(size_t)255;
    return p;
  };
  float* q0   = (float*)alloc((size_t)BN * C * 4);
  float* qkv  = (float*)alloc((size_t)BN * 3 * C * 4);
  float* sa   = (float*)alloc((size_t)BN * C * 4);
  float* tmp  = (float*)alloc((size_t)BN * C * 4);
  float* q1   = (float*)alloc((size_t)BN * C * 4);
  float* q2   = (float*)alloc((size_t)BN * C * 4);
  float* q3   = (float*)alloc((size_t)BN * C * 4);
  float* offb = (float*)alloc((size_t)BN * 192 * 4);
  float* awb  = (float*)alloc((size_t)BN * 96 * 4);
  float* ca   = (float*)alloc((size_t)BN * C * 4);
  float* ff   = (float*)alloc((size_t)BN * F * 4);
  __hip_bfloat16* v0 = (__hip_bfloat16*)alloc((size_t)B * 35200 * C * 2);
  __hip_bfloat16* v1 = (__hip_bfloat16*)alloc((size_t)B * 35200 * C * 2);
  __hip_bfloat16* v2 = (__hip_bfloat16*)alloc((size_t)B * 140800 * C * 2);

  dim3 tb(32, 8);

  // q0 = transpose(query): [B, C, N] -> [B, N, C]
  transpose_kernel<<<dim3(N / 32, C / 32, B), tb, 0, stream>>>(query, q0, C, N);

  // qkv = q0 @ in_proj_w.T + in_proj_b : [BN, 768]
  gemm128_kernel<false, float><<<dim3(BN / 128, 768 / 128), 256, 0, stream>>>(
      q0, C, 0, in_proj_w, in_proj_b, qkv, 768, 0, C, 0);

  // flash self-attention
  flash_attn_kernel<<<dim3(B * 8, N / 64), 256, 0, stream>>>(qkv, sa);

  // out proj + LN1
  gemm128_kernel<false, float><<<dim3(BN / 128, C / 128), 256, 0, stream>>>(
      sa, C, 0, out_proj_w, out_proj_b, tmp, C, 0, C, 0);
  add_ln_kernel<<<dim3(BN), 256, 0, stream>>>(tmp, q0, g1, be1, q1);

  // value projections (channels-major features, AT path), bf16 output, batched over B
  {
    const float* feats[3] = {bev, x_conv4, x_conv3};
    __hip_bfloat16* vals[3] = {v0, v1, v2};
    const int HWs[3] = {35200, 35200, 140800};
    for (int l = 0; l < 3; ++l)
      gemm128_kernel<true, __hip_bfloat16><<<dim3(HWs[l] / 128, C / 128, B), 256, 0, stream>>>(
          feats[l], HWs[l], (long)C * HWs[l], w_val, b_val,
          vals[l], C, (long)HWs[l] * C, C, 0);
  }

  // sampling offsets + attention weights (small N: 64-tile kernel with guards)
  gemm_kernel<<<dim3(BN / 64, 3), 256, 0, stream>>>(
      q1, C, w_off, b_off, offb, 192, BN, 192, C, 0);
  gemm_kernel<<<dim3(BN / 64, 2), 256, 0, stream>>>(
      q1, C, w_attn, b_attn, awb, 96, BN, 96, C, 0);

  // deformable sampling
  deform_kernel<<<dim3(BN), 256, 0, stream>>>(query_pos, offb, awb, v0, v1, v2, ca);

  // cross-attn output proj + LN2
  gemm128_kernel<false, float><<<dim3(BN / 128, C / 128), 256, 0, stream>>>(
      ca, C, 0, w_out, b_out, tmp, C, 0, C, 0);
  add_ln_kernel<<<dim3(BN), 256, 0, stream>>>(tmp, q1, g2, be2, q2);

  // FFN + LN3
  gemm128_kernel<false, float><<<dim3(BN / 128, F / 128), 256, 0, stream>>>(
      q2, C, 0, w_ff1, b_ff1, ff, F, 0, C, 1);
  gemm128_kernel<false, float><<<dim3(BN / 128, C / 128), 256, 0, stream>>>(
      ff, F, 0, w_ff2, b_ff2, tmp, C, 0, F, 0);
  add_ln_kernel<<<dim3(BN), 256, 0, stream>>>(tmp, q2, g3, be3, q3);

  // final transpose [B, N, C] -> [B, C, N]
  transpose_kernel<<<dim3(C / 32, N / 32, B), tb, 0, stream>>>(q3, (float*)d_out, N, C);
}

// Round 3
// 1260.551 us; speedup vs baseline: 2.3386x; 1.3740x over previous
//
#include <hip/hip_runtime.h>
#include <hip/hip_bf16.h>
#include <math.h>

// ---------------------------------------------------------------------------
// DeformTransformerDecoderLayer forward, MI355X
// B=2, C=256, N=1024, F=2048, heads=8, dh=32, levels=3, points=4
// Levels: (200,176), (200,176), (400,352)
// ---------------------------------------------------------------------------

typedef __attribute__((ext_vector_type(8))) short short8;
typedef __attribute__((ext_vector_type(4))) float f32x4;

__device__ inline unsigned short bf16bits(float x) {
  __hip_bfloat16 h = __float2bfloat16(x);
  return *(unsigned short*)&h;
}

__device__ inline void store8(float* p, const float v[8]) {
  *(float4*)p       = make_float4(v[0], v[1], v[2], v[3]);
  *(float4*)(p + 4) = make_float4(v[4], v[5], v[6], v[7]);
}

// ---------------------------------------------------------------------------
// MFMA value projection: out[m, n] = sum_k feat[k, m] * Wb[n, k] + bias[n]
// feat fp32 [256, HW] channel-major; Wb bf16 [256, 256]; out bf16 [HW, 256].
// Block: 256 thr (4 waves), tile 128(m) x 256(n) so feat is read exactly once.
// LDS rows unpadded (32 shorts = 64 B), 16B-block index XOR-swizzled by
// (row>>2)&3 -> frag ds_read_b128 land 2-way max (free, m136).
// ---------------------------------------------------------------------------
__global__ __launch_bounds__(256, 2) void valproj_kernel(
    const float* __restrict__ feat, long HW,
    const short* __restrict__ Wb,
    const float* __restrict__ bias,
    short* __restrict__ out)
{
  __shared__ short As[128 * 32];  // [m][k] bf16, swizzled blocks
  __shared__ short Bs[256 * 32];  // [n][k] bf16, swizzled blocks
  int t = threadIdx.x;
  int lane = t & 63, wave = t >> 6;
  long m0 = (long)blockIdx.x * 128;
  const float* fb = feat + (long)blockIdx.z * 256 * HW;
  short* ob = out + (long)blockIdx.z * HW * 256;

  int wm = (wave & 1) * 64, wn = (wave >> 1) * 128;

  f32x4 acc[4][8];
  #pragma unroll
  for (int i = 0; i < 4; ++i)
    #pragma unroll
    for (int j = 0; j < 8; ++j)
      acc[i][j] = (f32x4){0.f, 0.f, 0.f, 0.f};

  // A staging geometry: thread loads 4x4 fp32 block (4 m x 4 k)
  const int am = (t & 31) * 4;        // m base 0..124
  const int aks = t >> 5;             // k slot (4 shorts) 0..7
  const int ab = aks >> 1, ah = aks & 1;

  for (int k0 = 0; k0 < 256; k0 += 32) {
    // global loads first (overlap with previous iter's MFMA)
    float av[4][4];  // [kk][mm]
    #pragma unroll
    for (int kk = 0; kk < 4; ++kk)
      *(float4*)av[kk] = *(const float4*)(fb + (long)(k0 + aks * 4 + kk) * HW + m0 + am);
    short8 bv[4];
    int bn_[4], bb_[4];
    #pragma unroll
    for (int i = 0; i < 4; ++i) {
      int flat = t + i * 256;          // 0..1023
      int n = flat >> 2, b = flat & 3;
      bn_[i] = n; bb_[i] = b ^ ((n >> 2) & 3);
      bv[i] = *(const short8*)(Wb + (long)n * 256 + k0 + b * 8);
    }
    __syncthreads();  // previous iteration's frag reads complete

    // write A transposed: per mm, a 4-short k-run (8 B) at swizzled block
    #pragma unroll
    for (int mm = 0; mm < 4; ++mm) {
      int m = am + mm;
      int bsw = ab ^ ((m >> 2) & 3);
      unsigned short p0 = bf16bits(av[0][mm]);
      unsigned short p1 = bf16bits(av[1][mm]);
      unsigned short p2 = bf16bits(av[2][mm]);
      unsigned short p3 = bf16bits(av[3][mm]);
      unsigned d0 = (unsigned)p0 | ((unsigned)p1 << 16);
      unsigned d1 = (unsigned)p2 | ((unsigned)p3 << 16);
      unsigned* dst = (unsigned*)&As[m * 32 + bsw * 8 + ah * 4];
      dst[0] = d0; dst[1] = d1;
    }
    #pragma unroll
    for (int i = 0; i < 4; ++i)
      *(short8*)&Bs[bn_[i] * 32 + bb_[i] * 8] = bv[i];
    __syncthreads();  // staging visible

    // fragments + MFMA
    short8 af[4];
    {
      int q = lane >> 4, r = lane & 15;
      #pragma unroll
      for (int i = 0; i < 4; ++i) {
        int m = wm + i * 16 + r;
        af[i] = *(const short8*)&As[m * 32 + (q ^ ((m >> 2) & 3)) * 8];
      }
      #pragma unroll
      for (int j = 0; j < 8; ++j) {
        int n = wn + j * 16 + r;
        short8 bf = *(const short8*)&Bs[n * 32 + (q ^ ((n >> 2) & 3)) * 8];
        #pragma unroll
        for (int i = 0; i < 4; ++i)
          acc[i][j] = __builtin_amdgcn_mfma_f32_16x16x32_bf16(af[i], bf, acc[i][j], 0, 0, 0);
      }
    }
  }

  // epilogue: C/D layout col(n) = lane&15, row(m) = (lane>>4)*4 + reg
  int col = lane & 15, qrow = (lane >> 4) * 4;
  #pragma unroll
  for (int j = 0; j < 8; ++j) {
    int n = wn + j * 16 + col;
    float bvs = bias[n];
    #pragma unroll
    for (int i = 0; i < 4; ++i) {
      long mbase = m0 + wm + i * 16 + qrow;
      #pragma unroll
      for (int r = 0; r < 4; ++r) {
        __hip_bfloat16 h = __float2bfloat16(acc[i][j][r] + bvs);
        ob[(mbase + r) * 256 + n] = *(short*)&h;
      }
    }
  }
}

// w_val fp32 [256*256] -> bf16
__global__ __launch_bounds__(256) void convw_kernel(
    const float* __restrict__ in, short* __restrict__ out)
{
  int i = blockIdx.x * 256 + threadIdx.x;
  out[i] = (short)bf16bits(in[i]);
}

// ---------------------------------------------------------------------------
// fp32 GEMM 128x128 (qkv / out_proj / w_out / FFN): out = A @ W^T + bias
// ---------------------------------------------------------------------------
template<typename OutT>
__global__ __launch_bounds__(256) void gemm128_kernel(
    const float* __restrict__ A, long lda, long abstride,
    const float* __restrict__ W,
    const float* __restrict__ bias,
    OutT* __restrict__ out, long ldo, long obstride,
    int K, int relu)
{
  __shared__ float As[16][136];
  __shared__ float Ws[16][136];
  int t = threadIdx.x;
  int tx = t & 15, ty = t >> 4;
  long m0 = (long)blockIdx.x * 128, n0 = (long)blockIdx.y * 128;
  A += (long)blockIdx.z * abstride;
  out += (long)blockIdx.z * obstride;
  float acc[8][8] = {};

  for (int k0 = 0; k0 < K; k0 += 16) {
    float av[8];
    int a_mm = t >> 1, a_kc = (t & 1) * 8;
    {
      const float* src = A + (m0 + a_mm) * lda + k0 + a_kc;
      *(float4*)&av[0] = *(const float4*)src;
      *(float4*)&av[4] = *(const float4*)(src + 4);
    }
    float wv[8];
    int w_n = t >> 1, w_kc = (t & 1) * 8;
    {
      const float* src = W + (long)(n0 + w_n) * K + k0 + w_kc;
      *(float4*)&wv[0] = *(const float4*)src;
      *(float4*)&wv[4] = *(const float4*)(src + 4);
    }
    __syncthreads();
    #pragma unroll
    for (int j = 0; j < 8; ++j) As[a_kc + j][a_mm] = av[j];
    #pragma unroll
    for (int j = 0; j < 8; ++j) Ws[w_kc + j][w_n] = wv[j];
    __syncthreads();

    #pragma unroll
    for (int kk = 0; kk < 16; ++kk) {
      float a[8], b[8];
      *(float4*)&a[0] = *(float4*)&As[kk][ty * 8];
      *(float4*)&a[4] = *(float4*)&As[kk][ty * 8 + 4];
      *(float4*)&b[0] = *(float4*)&Ws[kk][tx * 8];
      *(float4*)&b[4] = *(float4*)&Ws[kk][tx * 8 + 4];
      #pragma unroll
      for (int i = 0; i < 8; ++i)
        #pragma unroll
        for (int j = 0; j < 8; ++j)
          acc[i][j] = fmaf(a[i], b[j], acc[i][j]);
    }
  }

  float bl[8];
  #pragma unroll
  for (int j = 0; j < 8; ++j) bl[j] = bias[n0 + tx * 8 + j];
  #pragma unroll
  for (int i = 0; i < 8; ++i) {
    float v[8];
    #pragma unroll
    for (int j = 0; j < 8; ++j) {
      float x = acc[i][j] + bl[j];
      v[j] = relu ? fmaxf(x, 0.f) : x;
    }
    store8(&out[(m0 + ty * 8 + i) * ldo + n0 + tx * 8], v);
  }
}

// Small GEMM (N=192 / N=96 projections): 64x64 tile, 4x4 per thread
__global__ __launch_bounds__(256) void gemm_kernel(
    const float* __restrict__ A, long lda,
    const float* __restrict__ W,
    const float* __restrict__ bias,
    float* __restrict__ out, long ldo,
    int M, int Nn, int K, int relu)
{
  __shared__ float As[16][65];
  __shared__ float Ws[16][65];
  int tid = threadIdx.x;
  int tx = tid & 15, ty = tid >> 4;
  int m0 = blockIdx.x * 64, n0 = blockIdx.y * 64;
  float acc[4][4] = {};

  for (int k0 = 0; k0 < K; k0 += 16) {
    #pragma unroll
    for (int i = 0; i < 4; ++i) {
      int idx = tid + i * 256;
      int mm = idx >> 4, kk = idx & 15;
      int m = m0 + mm;
      As[kk][mm] = (m < M) ? A[(long)m * lda + k0 + kk] : 0.f;
    }
    #pragma unroll
    for (int i = 0; i < 4; ++i) {
      int idx = tid + i * 256;
      int nn = idx >> 4, kk = idx & 15;
      int n = n0 + nn;
      Ws[kk][nn] = (n < Nn) ? W[(long)n * K + k0 + kk] : 0.f;
    }
    __syncthreads();
    #pragma unroll
    for (int kk = 0; kk < 16; ++kk) {
      float a[4], bb[4];
      #pragma unroll
      for (int i = 0; i < 4; ++i) a[i] = As[kk][ty * 4 + i];
      #pragma unroll
      for (int j = 0; j < 4; ++j) bb[j] = Ws[kk][tx * 4 + j];
      #pragma unroll
      for (int i = 0; i < 4; ++i)
        #pragma unroll
        for (int j = 0; j < 4; ++j)
          acc[i][j] += a[i] * bb[j];
    }
    __syncthreads();
  }

  #pragma unroll
  for (int i = 0; i < 4; ++i) {
    int m = m0 + ty * 4 + i;
    if (m >= M) continue;
    #pragma unroll
    for (int j = 0; j < 4; ++j) {
      int n = n0 + tx * 4 + j;
      if (n >= Nn) continue;
      float v = acc[i][j] + bias[n];
      if (relu) v = fmaxf(v, 0.f);
      out[(long)m * ldo + n] = v;
    }
  }
}

// in [B, R, Cc] -> out [B, Cc, R]
__global__ __launch_bounds__(256) void transpose_kernel(
    const float* __restrict__ in, float* __restrict__ out, int R, int Cc)
{
  __shared__ float tile[32][33];
  int b = blockIdx.z;
  int c0 = blockIdx.x << 5, r0 = blockIdx.y << 5;
  int tx = threadIdx.x, ty = threadIdx.y;  // 32 x 8
  const float* inb = in + (size_t)b * R * Cc;
  float* outb = out + (size_t)b * R * Cc;
  #pragma unroll
  for (int i = 0; i < 32; i += 8)
    tile[ty + i][tx] = inb[(size_t)(r0 + ty + i) * Cc + c0 + tx];
  __syncthreads();
  #pragma unroll
  for (int i = 0; i < 32; i += 8)
    outb[(size_t)(c0 + ty + i) * R + r0 + tx] = tile[tx][ty + i];
}

// ---------------------------------------------------------------------------
// Flash-style self-attention. Grid (B*8, N/64), 256 threads.
// ---------------------------------------------------------------------------
__global__ __launch_bounds__(256) void flash_attn_kernel(
    const float* __restrict__ qkv, float* __restrict__ sa)
{
  const int N = 1024;
  int bh = blockIdx.x;
  int b = bh >> 3, h = bh & 7;
  int q0 = blockIdx.y * 64;
  int t = threadIdx.x;
  int r = t >> 2, c4 = t & 3;

  __shared__ float Qs[64][36];
  __shared__ float Ks[64][36];
  __shared__ float Vs[64][36];
  __shared__ float Ps[64][68];

  {
    int row = t >> 2, col = (t & 3) * 8;
    const float* src = qkv + ((size_t)(b * N + q0 + row)) * 768 + h * 32 + col;
    float4 v0 = *(const float4*)src;
    float4 v1 = *(const float4*)(src + 4);
    const float s = 0.17677669529663687f;
    v0.x *= s; v0.y *= s; v0.z *= s; v0.w *= s;
    v1.x *= s; v1.y *= s; v1.z *= s; v1.w *= s;
    *(float4*)&Qs[row][col] = v0;
    *(float4*)&Qs[row][col + 4] = v1;
  }
  __syncthreads();
  float qreg[32];
  #pragma unroll
  for (int k = 0; k < 8; ++k)
    *(float4*)&qreg[k * 4] = *(float4*)&Qs[r][k * 4];

  float o[8] = {};
  float m = -INFINITY, l = 0.f;

  for (int kt = 0; kt < 16; ++kt) {
    int row = t >> 2, col = (t & 3) * 8;
    const float* kp = qkv + ((size_t)(b * N + kt * 64 + row)) * 768 + 256 + h * 32 + col;
    float4 k0 = *(const float4*)kp;
    float4 k1 = *(const float4*)(kp + 4);
    float4 v0 = *(const float4*)(kp + 256);
    float4 v1 = *(const float4*)(kp + 260);
    __syncthreads();
    *(float4*)&Ks[row][col] = k0;  *(float4*)&Ks[row][col + 4] = k1;
    *(float4*)&Vs[row][col] = v0;  *(float4*)&Vs[row][col + 4] = v1;
    __syncthreads();

    float sc[16];
    #pragma unroll
    for (int jj = 0; jj < 16; ++jj) {
      int j = c4 * 16 + jj;
      float s = 0.f;
      #pragma unroll
      for (int k8 = 0; k8 < 8; ++k8) {
        float4 kk4 = *(float4*)&Ks[j][k8 * 4];
        s = fmaf(qreg[k8 * 4 + 0], kk4.x, s);
        s = fmaf(qreg[k8 * 4 + 1], kk4.y, s);
        s = fmaf(qreg[k8 * 4 + 2], kk4.z, s);
        s = fmaf(qreg[k8 * 4 + 3], kk4.w, s);
      }
      sc[jj] = s;
    }
    float tm = sc[0];
    #pragma unroll
    for (int jj = 1; jj < 16; ++jj) tm = fmaxf(tm, sc[jj]);
    tm = fmaxf(tm, __shfl_xor(tm, 1));
    tm = fmaxf(tm, __shfl_xor(tm, 2));
    float mn = fmaxf(m, tm);
    float alpha = __expf(m - mn);
    float ls = 0.f;
    #pragma unroll
    for (int jj = 0; jj < 16; ++jj) {
      float p = __expf(sc[jj] - mn);
      Ps[r][c4 * 16 + jj] = p;
      ls += p;
    }
    ls += __shfl_xor(ls, 1);
    ls += __shfl_xor(ls, 2);
    l = l * alpha + ls;
    m = mn;
    #pragma unroll
    for (int d = 0; d < 8; ++d) o[d] *= alpha;
    __syncthreads();

    #pragma unroll 4
    for (int j = 0; j < 64; ++j) {
      float p = Ps[r][j];
      float4 w0 = *(float4*)&Vs[j][c4 * 8];
      float4 w1 = *(float4*)&Vs[j][c4 * 8 + 4];
      o[0] = fmaf(p, w0.x, o[0]); o[1] = fmaf(p, w0.y, o[1]);
      o[2] = fmaf(p, w0.z, o[2]); o[3] = fmaf(p, w0.w, o[3]);
      o[4] = fmaf(p, w1.x, o[4]); o[5] = fmaf(p, w1.y, o[5]);
      o[6] = fmaf(p, w1.z, o[6]); o[7] = fmaf(p, w1.w, o[7]);
    }
  }

  float inv = 1.f / l;
  float vout[8];
  #pragma unroll
  for (int d = 0; d < 8; ++d) vout[d] = o[d] * inv;
  store8(&sa[((size_t)(b * N + q0 + r)) * 256 + h * 32 + c4 * 8], vout);
}

// out = LayerNorm(x + res) * g + be, row = (b,n), C = 256
__global__ __launch_bounds__(256) void add_ln_kernel(
    const float* __restrict__ x, const float* __restrict__ res,
    const float* __restrict__ g, const float* __restrict__ be,
    float* __restrict__ out)
{
  int row = blockIdx.x, c = threadIdx.x;
  size_t base = (size_t)row * 256;
  float v = x[base + c] + res[base + c];
  __shared__ float red[256];
  red[c] = v;
  __syncthreads();
  for (int s = 128; s > 0; s >>= 1) { if (c < s) red[c] += red[c + s]; __syncthreads(); }
  float mean = red[0] * (1.f / 256.f);
  __syncthreads();
  float dv = v - mean;
  red[c] = dv * dv;
  __syncthreads();
  for (int s = 128; s > 0; s >>= 1) { if (c < s) red[c] += red[c + s]; __syncthreads(); }
  float var = red[0] * (1.f / 256.f);
  out[base + c] = dv * rsqrtf(var + 1e-5f) * g[c] + be[c];
}

// One block per (b,n); thread = (head h = t>>5, channel d = t&31)
__global__ __launch_bounds__(256) void deform_kernel(
    const float* __restrict__ query_pos,
    const float* __restrict__ offv,   // [B*N, 192] = [h][l][p][2]
    const float* __restrict__ awv,    // [B*N, 96]  = [h][l*p]
    const __hip_bfloat16* __restrict__ v0,
    const __hip_bfloat16* __restrict__ v1,
    const __hip_bfloat16* __restrict__ v2,
    float* __restrict__ ca)
{
  int bn = blockIdx.x;
  int b = bn >> 10;
  int t = threadIdx.x;
  int hh = t >> 5, d = t & 31;

  const float* awp = awv + (size_t)bn * 96 + hh * 24;
  float w[24];
  float mx = -1e30f;
  #pragma unroll
  for (int i = 0; i < 24; ++i) { w[i] = awp[i]; mx = fmaxf(mx, w[i]); }
  float s = 0.f;
  #pragma unroll
  for (int i = 0; i < 24; ++i) { w[i] = __expf(w[i] - mx); s += w[i]; }
  float inv = 1.f / s;

  float rx = query_pos[bn * 2 + 0] * (1.f / 352.f);
  float ry = query_pos[bn * 2 + 1] * (1.f / 400.f);
  const float* offp = offv + (size_t)bn * 192 + hh * 24;

  const __hip_bfloat16* vb[3] = {v0, v1, v2};
  const int Hs[3] = {200, 200, 400};
  const int Wss[3] = {176, 176, 352};

  float acc = 0.f;
  #pragma unroll
  for (int l = 0; l < 3; ++l) {
    int H = Hs[l], W = Wss[l], HW = H * W;
    const __hip_bfloat16* vl = vb[l] + (size_t)b * HW * 256 + hh * 32 + d;
    float fx = rx * (float)W, fy = ry * (float)H;
    #pragma unroll
    for (int p = 0; p < 4; ++p) {
      float x = fx + offp[l * 8 + p * 2 + 0] - 0.5f;
      float y = fy + offp[l * 8 + p * 2 + 1] - 0.5f;
      float x0f = floorf(x), y0f = floorf(y);
      float wx = x - x0f, wy = y - y0f;
      int x0 = (int)x0f, y0 = (int)y0f;
      float wgt = w[l * 4 + p] * inv;
      bool xin0 = (x0 >= 0) & (x0 < W);
      bool xin1 = (x0 + 1 >= 0) & (x0 + 1 < W);
      bool yin0 = (y0 >= 0) & (y0 < H);
      bool yin1 = (y0 + 1 >= 0) & (y0 + 1 < H);
      float v00 = 0.f, v10 = 0.f, v01 = 0.f, v11 = 0.f;
      if (yin0) {
        size_t rowo = (size_t)(y0 * W) * 256;
        if (xin0) v00 = __bfloat162float(vl[rowo + (size_t)x0 * 256]);
        if (xin1) v10 = __bfloat162float(vl[rowo + (size_t)(x0 + 1) * 256]);
      }
      if (yin1) {
        size_t rowo = (size_t)((y0 + 1) * W) * 256;
        if (xin0) v01 = __bfloat162float(vl[rowo + (size_t)x0 * 256]);
        if (xin1) v11 = __bfloat162float(vl[rowo + (size_t)(x0 + 1) * 256]);
      }
      acc += wgt * ((1.f - wx) * (1.f - wy) * v00 + wx * (1.f - wy) * v10 +
                    (1.f - wx) * wy * v01 + wx * wy * v11);
    }
  }
  ca[(size_t)bn * 256 + t] = acc;
}

extern "C" void kernel_launch(void* const* d_in, const int* in_sizes, int n_in,
                              void* d_out, int out_size, void* d_ws, size_t ws_size,
                              hipStream_t stream)
{
  const float* query      = (const float*)d_in[0];
  const float* query_pos  = (const float*)d_in[1];
  const float* bev        = (const float*)d_in[2];
  const float* x_conv4    = (const float*)d_in[3];
  const float* x_conv3    = (const float*)d_in[4];
  const float* in_proj_w  = (const float*)d_in[5];
  const float* in_proj_b  = (const float*)d_in[6];
  const float* out_proj_w = (const float*)d_in[7];
  const float* out_proj_b = (const float*)d_in[8];
  const float* w_off      = (const float*)d_in[9];
  const float* b_off      = (const float*)d_in[10];
  const float* w_attn     = (const float*)d_in[11];
  const float* b_attn     = (const float*)d_in[12];
  const float* w_val      = (const float*)d_in[13];
  const float* b_val      = (const float*)d_in[14];
  const float* w_out      = (const float*)d_in[15];
  const float* b_out      = (const float*)d_in[16];
  const float* w_ff1      = (const float*)d_in[17];
  const float* b_ff1      = (const float*)d_in[18];
  const float* w_ff2      = (const float*)d_in[19];
  const float* b_ff2      = (const float*)d_in[20];
  const float* g1         = (const float*)d_in[21];
  const float* be1        = (const float*)d_in[22];
  const float* g2         = (const float*)d_in[23];
  const float* be2        = (const float*)d_in[24];
  const float* g3         = (const float*)d_in[25];
  const float* be3        = (const float*)d_in[26];

  const int B = 2, N = 1024, C = 256, F = 2048;
  const int BN = B * N;

  char* wp = (char*)d_ws;
  auto alloc = [&](size_t bytes) -> void* {
    void* p = (void*)wp;
    wp += (bytes + 255) & ~(size_t)255;
    return p;
  };
  float* q0   = (float*)alloc((size_t)BN * C * 4);
  float* qkv  = (float*)alloc((size_t)BN * 3 * C * 4);
  float* sa   = (float*)alloc((size_t)BN * C * 4);
  float* tmp  = (float*)alloc((size_t)BN * C * 4);
  float* q1   = (float*)alloc((size_t)BN * C * 4);
  float* q2   = (float*)alloc((size_t)BN * C * 4);
  float* q3   = (float*)alloc((size_t)BN * C * 4);
  float* offb = (float*)alloc((size_t)BN * 192 * 4);
  float* awb  = (float*)alloc((size_t)BN * 96 * 4);
  float* ca   = (float*)alloc((size_t)BN * C * 4);
  float* ff   = (float*)alloc((size_t)BN * F * 4);
  __hip_bfloat16* v0 = (__hip_bfloat16*)alloc((size_t)B * 35200 * C * 2);
  __hip_bfloat16* v1 = (__hip_bfloat16*)alloc((size_t)B * 35200 * C * 2);
  __hip_bfloat16* v2 = (__hip_bfloat16*)alloc((size_t)B * 140800 * C * 2);
  short* wvb = (short*)alloc((size_t)C * C * 2);

  dim3 tb(32, 8);

  // q0 = transpose(query): [B, C, N] -> [B, N, C]
  transpose_kernel<<<dim3(N / 32, C / 32, B), tb, 0, stream>>>(query, q0, C, N);

  // qkv = q0 @ in_proj_w.T + in_proj_b : [BN, 768]
  gemm128_kernel<float><<<dim3(BN / 128, 768 / 128), 256, 0, stream>>>(
      q0, C, 0, in_proj_w, in_proj_b, qkv, 768, 0, C, 0);

  // flash self-attention
  flash_attn_kernel<<<dim3(B * 8, N / 64), 256, 0, stream>>>(qkv, sa);

  // out proj + LN1
  gemm128_kernel<float><<<dim3(BN / 128, C / 128), 256, 0, stream>>>(
      sa, C, 0, out_proj_w, out_proj_b, tmp, C, 0, C, 0);
  add_ln_kernel<<<dim3(BN), 256, 0, stream>>>(tmp, q0, g1, be1, q1);

  // value projections: bf16 MFMA with fused transpose-convert staging
  convw_kernel<<<dim3(C * C / 256), 256, 0, stream>>>(w_val, wvb);
  {
    const float* feats[3] = {bev, x_conv4, x_conv3};
    __hip_bfloat16* vals[3] = {v0, v1, v2};
    const long HWs[3] = {35200, 35200, 140800};
    for (int l = 0; l < 3; ++l)
      valproj_kernel<<<dim3(HWs[l] / 128, 1, B), 256, 0, stream>>>(
          feats[l], HWs[l], wvb, b_val, (short*)vals[l]);
  }

  // sampling offsets + attention weights
  gemm_kernel<<<dim3(BN / 64, 3), 256, 0, stream>>>(
      q1, C, w_off, b_off, offb, 192, BN, 192, C, 0);
  gemm_kernel<<<dim3(BN / 64, 2), 256, 0, stream>>>(
      q1, C, w_attn, b_attn, awb, 96, BN, 96, C, 0);

  // deformable sampling
  deform_kernel<<<dim3(BN), 256, 0, stream>>>(query_pos, offb, awb, v0, v1, v2, ca);

  // cross-attn output proj + LN2
  gemm128_kernel<float><<<dim3(BN / 128, C / 128), 256, 0, stream>>>(
      ca, C, 0, w_out, b_out, tmp, C, 0, C, 0);
  add_ln_kernel<<<dim3(BN), 256, 0, stream>>>(tmp, q1, g2, be2, q2);

  // FFN + LN3
  gemm128_kernel<float><<<dim3(BN / 128, F / 128), 256, 0, stream>>>(
      q2, C, 0, w_ff1, b_ff1, ff, F, 0, C, 1);
  gemm128_kernel<float><<<dim3(BN / 128, C / 128), 256, 0, stream>>>(
      ff, F, 0, w_ff2, b_ff2, tmp, C, 0, F, 0);
  add_ln_kernel<<<dim3(BN), 256, 0, stream>>>(tmp, q2, g3, be3, q3);

  // final transpose [B, N, C] -> [B, C, N]
  transpose_kernel<<<dim3(C / 32, N / 32, B), tb, 0, stream>>>(q3, (float*)d_out, N, C);
}